// Round 2
// baseline (230.117 us; speedup 1.0000x reference)
//
#include <hip/hip_runtime.h>

// YOLO loss forward on MI355X.
// input/target: (B=256, C=25, S=64, S=64) fp32, row-major.
// Memory-bound reduction: 209.7 MB -> 1 float. Roofline ~33 us at 6.3 TB/s.
//
// V3: attack per-wave MLP. V1/V2 both compiled to VGPR=32 -> compiler
// serialized the load streams (load->waitcnt->use), ~1-2 wave-loads in
// flight -> latency-bound at 3.5 TB/s delivered. Changes:
//  - __launch_bounds__(256, 4): 128-VGPR budget, 16 waves/CU.
//  - class loop: 4 items batched, all 12 loads issued before any use.
//  - objectness mask precomputed to 1 MB uchar4 workspace (L2-hot),
//    removing the 20x re-stream of the t4 plane.

#define COORD 5.0f
#define NOOBJ 0.5f

constexpr int B = 256;
constexpr int C = 25;
constexpr int S = 64;
constexpr int SS = S * S;                    // 4096 spatial positions per image
constexpr int CH_STRIDE4 = SS / 4;           // 1024 float4 per channel plane
constexpr int IMG_STRIDE4 = C * CH_STRIDE4;  // 25600 float4 per image
constexpr int N4 = B * SS / 4;               // 262144 float4-groups (= 2^18)

constexpr int THREADS = 256;
constexpr int CLASS_CH = 20;                            // channels 5..24
constexpr int CLASS_ITEMS = CLASS_CH * N4;              // 5,242,880
constexpr int CLASS_BLOCKS = 2560;
constexpr int CLASS_THREADS_TOT = CLASS_BLOCKS * THREADS; // 655,360
constexpr int CLASS_IPT = CLASS_ITEMS / CLASS_THREADS_TOT; // 8 items/thread
constexpr int BOX_BLOCKS = N4 / THREADS;                // 1024
constexpr int TOTAL_BLOCKS = CLASS_BLOCKS + BOX_BLOCKS; // 3584
constexpr int MASK_BYTES = N4 * 4;                      // uchar4 per group, 1 MB

__device__ __forceinline__ float comp(const float4 v, int k) {
    switch (k) {
        case 0: return v.x;
        case 1: return v.y;
        case 2: return v.z;
        default: return v.w;
    }
}

__global__ void zero_out_kernel(float* out) { out[0] = 0.0f; }

// One uchar4 (0/1 flags) per float4-group: mask[g] = (t4 > 0).
__global__ __launch_bounds__(256) void mask_kernel(
        const float4* __restrict__ tg, uchar4* __restrict__ mask) {
    const int g = blockIdx.x * 256 + threadIdx.x;  // grid = N4/256 blocks
    const float4 t4 = tg[(g >> 10) * IMG_STRIDE4 + (g & 1023) + 4 * CH_STRIDE4];
    mask[g] = make_uchar4(t4.x > 0.0f, t4.y > 0.0f, t4.z > 0.0f, t4.w > 0.0f);
}

__global__ __launch_bounds__(256, 4) void yolo_loss_kernel(
        const float4* __restrict__ in, const float4* __restrict__ tg,
        const uchar4* __restrict__ mask,  // may be null -> recompute from tg
        float* __restrict__ out) {
    float acc = 0.0f;

    if (blockIdx.x < CLASS_BLOCKS) {
        // ---- class terms: sum m * (p_c - t_c)^2 over channels 5..24 ----
        const int t = blockIdx.x * THREADS + threadIdx.x;
        #pragma unroll
        for (int i = 0; i < CLASS_IPT; i += 4) {
            float4 pv[4], tv[4];
            uchar4 mk[4];
            // Issue all 12 loads before any consumption.
            #pragma unroll
            for (int u = 0; u < 4; ++u) {
                const int itm = t + (i + u) * CLASS_THREADS_TOT;
                const int c = 5 + (itm >> 18);       // N4 = 2^18
                const int g = itm & (N4 - 1);
                const int base = (g >> 10) * IMG_STRIDE4 + (g & 1023);
                pv[u] = in[base + c * CH_STRIDE4];
                tv[u] = tg[base + c * CH_STRIDE4];
                if (mask) {
                    mk[u] = mask[g];
                } else {
                    const float4 t4 = tg[base + 4 * CH_STRIDE4];
                    mk[u] = make_uchar4(t4.x > 0.0f, t4.y > 0.0f,
                                        t4.z > 0.0f, t4.w > 0.0f);
                }
            }
            #pragma unroll
            for (int u = 0; u < 4; ++u) {
                float d;
                d = pv[u].x - tv[u].x; if (mk[u].x) acc += d * d;
                d = pv[u].y - tv[u].y; if (mk[u].y) acc += d * d;
                d = pv[u].z - tv[u].z; if (mk[u].z) acc += d * d;
                d = pv[u].w - tv[u].w; if (mk[u].w) acc += d * d;
            }
        }
    } else {
        // ---- box terms: channels 0..4 (coord + iou + conf + noobj) ----
        const int g = (blockIdx.x - CLASS_BLOCKS) * THREADS + threadIdx.x; // < N4
        const int base = (g >> 10) * IMG_STRIDE4 + (g & 1023);

        // 10 independent loads, issued together (128-VGPR budget).
        const float4 p0 = in[base + 0 * CH_STRIDE4];
        const float4 p1 = in[base + 1 * CH_STRIDE4];
        const float4 p2 = in[base + 2 * CH_STRIDE4];
        const float4 p3 = in[base + 3 * CH_STRIDE4];
        const float4 p4 = in[base + 4 * CH_STRIDE4];
        const float4 t0 = tg[base + 0 * CH_STRIDE4];
        const float4 t1 = tg[base + 1 * CH_STRIDE4];
        const float4 t2 = tg[base + 2 * CH_STRIDE4];
        const float4 t3 = tg[base + 3 * CH_STRIDE4];
        const float4 t4 = tg[base + 4 * CH_STRIDE4];

        const float invBlocks = 1.0f / (float)S;
        #pragma unroll
        for (int k = 0; k < 4; ++k) {
            const float px = comp(p0, k), py = comp(p1, k);
            const float pw = comp(p2, k), ph = comp(p3, k);
            const float pc = comp(p4, k);
            const float tx = comp(t0, k), ty = comp(t1, k);
            const float tw = comp(t2, k), th = comp(t3, k);
            const float tc = comp(t4, k);
            const float m = (tc > 0.0f) ? 1.0f : 0.0f;

            // IoU (forward values only)
            const float c1x = px * invBlocks, c1y = py * invBlocks;
            const float c2x = tx * invBlocks, c2y = ty * invBlocks;
            const float x1a = c1x - pw * 0.5f, x2a = c1x + pw * 0.5f;
            const float y1a = c1y - ph * 0.5f, y2a = c1y + ph * 0.5f;
            const float x1b = c2x - tw * 0.5f, x2b = c2x + tw * 0.5f;
            const float y1b = c2y - th * 0.5f, y2b = c2y + th * 0.5f;
            const float dx = fminf(x2a, x2b) - fmaxf(x1a, x1b);
            const float dy = fminf(y2a, y2b) - fmaxf(y1a, y1b);
            const float inter = dx * dy;
            const float uni = pw * ph + tw * th - inter;
            const bool pos = (dx > 0.0f) && (dy > 0.0f);
            const float iou = pos ? (inter / uni) : 0.0f;

            // coord terms
            const float ex = px - tx, ey = py - ty;
            acc += COORD * m * (ex * ex + ey * ey);
            const float sw = sqrtf(pw) - sqrtf(tw);
            const float sh = sqrtf(ph) - sqrtf(th);
            acc += COORD * m * (sw * sw + sh * sh);
            // confidence terms
            const float ec = pc - iou;
            acc += m * ec * ec;
            acc += NOOBJ * (1.0f - m) * (pc * pc);
        }
    }

    // wave64 reduce
    #pragma unroll
    for (int off = 32; off > 0; off >>= 1)
        acc += __shfl_down(acc, off, 64);

    __shared__ float smem[4];
    const int lane = threadIdx.x & 63;
    const int wid = threadIdx.x >> 6;
    if (lane == 0) smem[wid] = acc;
    __syncthreads();
    if (threadIdx.x == 0) {
        const float s = smem[0] + smem[1] + smem[2] + smem[3];
        atomicAdd(out, s);
    }
}

extern "C" void kernel_launch(void* const* d_in, const int* in_sizes, int n_in,
                              void* d_out, int out_size, void* d_ws, size_t ws_size,
                              hipStream_t stream) {
    const float4* in = (const float4*)d_in[0];
    const float4* tg = (const float4*)d_in[1];
    float* out = (float*)d_out;

    // d_out is re-poisoned to 0xAA before every timed launch -> zero it first.
    zero_out_kernel<<<1, 1, 0, stream>>>(out);

    uchar4* mask = nullptr;
    if (d_ws != nullptr && ws_size >= (size_t)MASK_BYTES) {
        mask = (uchar4*)d_ws;
        mask_kernel<<<N4 / 256, 256, 0, stream>>>(tg, mask);
    }

    yolo_loss_kernel<<<TOTAL_BLOCKS, THREADS, 0, stream>>>(in, tg, mask, out);
}